// Round 1
// baseline (625.648 us; speedup 1.0000x reference)
//
#include <hip/hip_runtime.h>

#define B_ 2
#define S_ 2048
#define E_ 1024
#define H_ 16
#define D_ 64
#define BS_ (B_*S_)

typedef unsigned short u16;
typedef __attribute__((ext_vector_type(8))) short short8;
typedef __attribute__((ext_vector_type(4))) float floatx4;
typedef __bf16 bf16x8 __attribute__((ext_vector_type(8)));

__device__ __forceinline__ u16 f2bf(float f) {
    unsigned int u = __builtin_bit_cast(unsigned int, f);
    u += 0x7FFFu + ((u >> 16) & 1u);
    return (u16)(u >> 16);
}
__device__ __forceinline__ float bf2f(u16 h) {
    return __builtin_bit_cast(float, (unsigned int)h << 16);
}
__device__ __forceinline__ floatx4 mfma16(short8 a, short8 b, floatx4 c) {
    return __builtin_amdgcn_mfma_f32_16x16x32_bf16(
        __builtin_bit_cast(bf16x8, a), __builtin_bit_cast(bf16x8, b), c, 0, 0, 0);
}

// ---------------- prep kernels ----------------

__global__ __launch_bounds__(256) void rope_table_kernel(float* __restrict__ cost,
                                                         float* __restrict__ sint) {
    int idx = blockIdx.x * 256 + threadIdx.x;   // S_*32
    int s = idx >> 5, i = idx & 31;
    float inv = powf(10000.0f, -(float)i / 32.0f);
    float a = (float)s * inv;
    cost[idx] = cosf(a);
    sint[idx] = sinf(a);
}

__global__ __launch_bounds__(256) void convert_x_kernel(const float* __restrict__ X,
                                                        u16* __restrict__ Xb,
                                                        u16* __restrict__ Xlb) {
    int i = blockIdx.x * 256 + threadIdx.x;     // BS_*E_/4 float4s
    float4 v = ((const float4*)X)[i];
    u16 h0 = f2bf(v.x), h1 = f2bf(v.y), h2 = f2bf(v.z), h3 = f2bf(v.w);
    uint2 o;
    o.x = (unsigned)h0 | ((unsigned)h1 << 16);
    o.y = (unsigned)h2 | ((unsigned)h3 << 16);
    ((uint2*)Xb)[i] = o;
    u16 l0 = f2bf(v.x - bf2f(h0)), l1 = f2bf(v.y - bf2f(h1));
    u16 l2 = f2bf(v.z - bf2f(h2)), l3 = f2bf(v.w - bf2f(h3));
    uint2 ol;
    ol.x = (unsigned)l0 | ((unsigned)l1 << 16);
    ol.y = (unsigned)l2 | ((unsigned)l3 << 16);
    ((uint2*)Xlb)[i] = ol;
}

// W [K][N] fp32 -> Wt [N][K] bf16 (+ optional residual)
__global__ __launch_bounds__(256) void transpose_w_kernel(const float* __restrict__ W,
                                                          u16* __restrict__ Wt,
                                                          u16* __restrict__ Wlt) {
    __shared__ float t[32][33];
    int ntn = E_ / 32;
    int bx = blockIdx.x;
    int tk = (bx / ntn) * 32, tn = (bx % ntn) * 32;
    int tx = threadIdx.x & 31, ty = threadIdx.x >> 5;   // 32 x 8
    for (int i = 0; i < 32; i += 8)
        t[ty + i][tx] = W[(size_t)(tk + ty + i) * E_ + tn + tx];
    __syncthreads();
    for (int i = 0; i < 32; i += 8) {
        float v = t[tx][ty + i];
        u16 hi = f2bf(v);
        Wt[(size_t)(tn + ty + i) * E_ + tk + tx] = hi;
        if (Wlt) Wlt[(size_t)(tn + ty + i) * E_ + tk + tx] = f2bf(v - bf2f(hi));
    }
}

// ---------------- bf16 MFMA GEMM: C[M][N] (+)= A[M][K] @ Bt[N][K]^T ----------------
#define GLDA 72
__global__ __launch_bounds__(256) void gemm_bf16_kernel(const u16* __restrict__ A,
                                                        const u16* __restrict__ Bt,
                                                        float* __restrict__ C,
                                                        int M, int N, int Kd, int accum) {
    __shared__ __align__(16) u16 lA[128 * GLDA];
    __shared__ __align__(16) u16 lB[128 * GLDA];
    int tid = threadIdx.x;
    int lane = tid & 63, wave = tid >> 6;
    int nbn = N / 128;
    int m0 = (blockIdx.x / nbn) * 128, n0 = (blockIdx.x % nbn) * 128;
    int wm = (wave >> 1) * 64, wn = (wave & 1) * 64;
    int lr = lane & 15, lk = (lane >> 4) * 8;

    floatx4 acc[4][4];
#pragma unroll
    for (int i = 0; i < 4; ++i)
#pragma unroll
        for (int j = 0; j < 4; ++j) acc[i][j] = (floatx4){0.f, 0.f, 0.f, 0.f};

    for (int k0 = 0; k0 < Kd; k0 += 64) {
#pragma unroll
        for (int i = 0; i < 4; ++i) {
            int chunk = tid + i * 256;      // 1024 chunks of 16B
            int r = chunk >> 3;
            int c = (chunk & 7) * 8;
            *(uint4*)&lA[r * GLDA + c] = *(const uint4*)&A[(size_t)(m0 + r) * Kd + k0 + c];
            *(uint4*)&lB[r * GLDA + c] = *(const uint4*)&Bt[(size_t)(n0 + r) * Kd + k0 + c];
        }
        __syncthreads();
#pragma unroll
        for (int kk = 0; kk < 64; kk += 32) {
            short8 afr[4], bfr[4];
#pragma unroll
            for (int mi = 0; mi < 4; ++mi)
                afr[mi] = *(const short8*)&lA[(wm + mi * 16 + lr) * GLDA + kk + lk];
#pragma unroll
            for (int ni = 0; ni < 4; ++ni)
                bfr[ni] = *(const short8*)&lB[(wn + ni * 16 + lr) * GLDA + kk + lk];
#pragma unroll
            for (int mi = 0; mi < 4; ++mi)
#pragma unroll
                for (int ni = 0; ni < 4; ++ni)
                    acc[mi][ni] = mfma16(afr[mi], bfr[ni], acc[mi][ni]);
        }
        __syncthreads();
    }
    int lq = lane >> 4;
#pragma unroll
    for (int mi = 0; mi < 4; ++mi)
#pragma unroll
        for (int ni = 0; ni < 4; ++ni)
#pragma unroll
            for (int r = 0; r < 4; ++r) {
                size_t row = m0 + wm + mi * 16 + lq * 4 + r;
                size_t col = n0 + wn + ni * 16 + lr;
                if (accum) C[row * N + col] += acc[mi][ni][r];
                else       C[row * N + col]  = acc[mi][ni][r];
            }
}

// ---------------- fp32 q for the last token (exact path for top-k) ----------------
__global__ __launch_bounds__(256) void qlast_kernel(const float* __restrict__ x,
                                                    const float* __restrict__ wq,
                                                    float* __restrict__ qlast) {
    int j = blockIdx.x * 256 + threadIdx.x;     // 0..B_*E_-1
    int b = j >> 10, col = j & 1023;
    const float* xr = &x[((size_t)b * S_ + (S_ - 1)) * E_];
    float acc = 0.f;
    for (int e = 0; e < E_; ++e) acc = fmaf(xr[e], wq[(size_t)e * E_ + col], acc);
    qlast[j] = acc;
}

// ---------------- RoPE + rearrange q,k to [b][h][s][d] bf16 ----------------
__global__ __launch_bounds__(256) void rope_qk_kernel(const float* __restrict__ qf,
                                                      const float* __restrict__ kf,
                                                      const float* __restrict__ cost,
                                                      const float* __restrict__ sint,
                                                      u16* __restrict__ qb,
                                                      u16* __restrict__ kb) {
    int idx = blockIdx.x * 256 + threadIdx.x;   // B_*S_*H_*32 = 2^21
    int i = idx & 31;
    int h = (idx >> 5) & 15;
    int s = (idx >> 9) & 2047;
    int b = idx >> 20;
    float c = cost[s * 32 + i], sn = sint[s * 32 + i];
    size_t src = ((size_t)b * S_ + s) * E_ + h * 64 + 2 * i;
    float q0 = qf[src], q1 = qf[src + 1];
    float k0 = kf[src], k1 = kf[src + 1];
    size_t dst = (((size_t)(b * H_ + h) * S_) + s) * D_ + 2 * i;
    unsigned qo = (unsigned)f2bf(q0 * c - q1 * sn) | ((unsigned)f2bf(q0 * sn + q1 * c) << 16);
    unsigned ko = (unsigned)f2bf(k0 * c - k1 * sn) | ((unsigned)f2bf(k0 * sn + k1 * c) << 16);
    *(unsigned*)&qb[dst] = qo;
    *(unsigned*)&kb[dst] = ko;
}

// ---------------- V -> vtb [b][h][d][s] bf16 (LDS-tiled transpose) ----------------
__global__ __launch_bounds__(256) void v_transpose_kernel(const float* __restrict__ vf,
                                                          u16* __restrict__ vtb) {
    __shared__ float t[64][65];
    int bx = blockIdx.x;            // b*512 + h*32 + sc
    int sc = bx & 31;
    int h = (bx >> 5) & 15;
    int b = bx >> 9;
    int s0 = sc * 64;
    int tid = threadIdx.x;
    int d = tid & 63, sr = tid >> 6;
    for (int j = 0; j < 64; j += 4)
        t[sr + j][d] = vf[((size_t)b * S_ + s0 + sr + j) * E_ + h * 64 + d];
    __syncthreads();
    int sj = tid & 63, dr = tid >> 6;
    for (int j = 0; j < 64; j += 4)
        vtb[(((size_t)(b * H_ + h)) * D_ + dr + j) * S_ + s0 + sj] = f2bf(t[sj][dr + j]);
}

// ---------------- flash attention (causal), 1 wave per 16-row q tile ----------------
__global__ __launch_bounds__(256) void flash_kernel(const u16* __restrict__ qb,
                                                    const u16* __restrict__ kb,
                                                    const u16* __restrict__ vtb,
                                                    u16* __restrict__ ab) {
    __shared__ __align__(16) u16 ldsP[4][16 * 40];   // per-wave, padded stride 40
    int tid = threadIdx.x;
    int lane = tid & 63, wave = tid >> 6;
    int bx = blockIdx.x;            // b*512 + h*32 + qc
    int qc = bx & 31, h = (bx >> 5) & 15, b = bx >> 9;
    int qt0 = qc * 64 + wave * 16;
    size_t bh = (size_t)(b * H_ + h);
    const u16* Q = qb + bh * S_ * D_;
    const u16* K = kb + bh * S_ * D_;
    const u16* V = vtb + bh * D_ * S_;
    u16* lp = &ldsP[wave][0];

    int lr = lane & 15, lq = lane >> 4, lk = lq * 8;
    short8 qfr0 = *(const short8*)&Q[(size_t)(qt0 + lr) * D_ + lk];
    short8 qfr1 = *(const short8*)&Q[(size_t)(qt0 + lr) * D_ + 32 + lk];

    floatx4 o0 = {0, 0, 0, 0}, o1 = {0, 0, 0, 0}, o2 = {0, 0, 0, 0}, o3 = {0, 0, 0, 0};
    float mrow[4] = {-1e30f, -1e30f, -1e30f, -1e30f};
    float lrow[4] = {0, 0, 0, 0};
    int nend = qt0 + 16;
    for (int n0 = 0; n0 < nend; n0 += 32) {
        floatx4 s0acc = {0, 0, 0, 0}, s1acc = {0, 0, 0, 0};
        {
            const u16* Kr0 = &K[(size_t)(n0 + lr) * D_];
            s0acc = mfma16(qfr0, *(const short8*)&Kr0[lk], s0acc);
            s0acc = mfma16(qfr1, *(const short8*)&Kr0[32 + lk], s0acc);
            const u16* Kr1 = &K[(size_t)(n0 + 16 + lr) * D_];
            s1acc = mfma16(qfr0, *(const short8*)&Kr1[lk], s1acc);
            s1acc = mfma16(qfr1, *(const short8*)&Kr1[32 + lk], s1acc);
        }
        float sv[2][4];
        int col0 = n0 + lr, col1 = n0 + 16 + lr;
#pragma unroll
        for (int r = 0; r < 4; ++r) {
            int row = qt0 + lq * 4 + r;
            sv[0][r] = (col0 <= row) ? s0acc[r] * 0.125f : -1e30f;
            sv[1][r] = (col1 <= row) ? s1acc[r] * 0.125f : -1e30f;
        }
        float p[2][4], alpha[4];
#pragma unroll
        for (int r = 0; r < 4; ++r) {
            float rmax = fmaxf(sv[0][r], sv[1][r]);
#pragma unroll
            for (int m = 1; m <= 8; m <<= 1) rmax = fmaxf(rmax, __shfl_xor(rmax, m));
            float mn = fmaxf(mrow[r], rmax);
            float a = __expf(mrow[r] - mn);
            p[0][r] = __expf(sv[0][r] - mn);
            p[1][r] = __expf(sv[1][r] - mn);
            float ps = p[0][r] + p[1][r];
#pragma unroll
            for (int m = 1; m <= 8; m <<= 1) ps += __shfl_xor(ps, m);
            lrow[r] = lrow[r] * a + ps;
            mrow[r] = mn;
            alpha[r] = a;
        }
#pragma unroll
        for (int r = 0; r < 4; ++r) {
            o0[r] *= alpha[r]; o1[r] *= alpha[r]; o2[r] *= alpha[r]; o3[r] *= alpha[r];
        }
#pragma unroll
        for (int r = 0; r < 4; ++r) {
            lp[(lq * 4 + r) * 40 + lr]      = f2bf(p[0][r]);
            lp[(lq * 4 + r) * 40 + 16 + lr] = f2bf(p[1][r]);
        }
        asm volatile("s_waitcnt lgkmcnt(0)" ::: "memory");
        short8 pfr = *(const short8*)&lp[lr * 40 + lk];
        o0 = mfma16(pfr, *(const short8*)&V[(size_t)(0 * 16 + lr) * S_ + n0 + lk], o0);
        o1 = mfma16(pfr, *(const short8*)&V[(size_t)(1 * 16 + lr) * S_ + n0 + lk], o1);
        o2 = mfma16(pfr, *(const short8*)&V[(size_t)(2 * 16 + lr) * S_ + n0 + lk], o2);
        o3 = mfma16(pfr, *(const short8*)&V[(size_t)(3 * 16 + lr) * S_ + n0 + lk], o3);
    }
    float inv[4];
#pragma unroll
    for (int r = 0; r < 4; ++r) inv[r] = 1.0f / lrow[r];
    size_t orow_base = ((size_t)b * S_ + qt0 + lq * 4) * E_ + h * D_;
#pragma unroll
    for (int r = 0; r < 4; ++r) {
        size_t rb = orow_base + (size_t)r * E_;
        ab[rb + 0  + lr] = f2bf(o0[r] * inv[r]);
        ab[rb + 16 + lr] = f2bf(o1[r] * inv[r]);
        ab[rb + 32 + lr] = f2bf(o2[r] * inv[r]);
        ab[rb + 48 + lr] = f2bf(o3[r] * inv[r]);
    }
}

// ---------------- top-8 tiles from last-row logits (fp32 path) ----------------
__global__ __launch_bounds__(256) void topk_kernel(const float* __restrict__ qlast,
                                                   const float* __restrict__ kf,
                                                   const float* __restrict__ cost,
                                                   const float* __restrict__ sint,
                                                   float* __restrict__ oidx) {
    __shared__ float qr[64];
    __shared__ float lmax[256];
    __shared__ float tmax[128];
    int bx = blockIdx.x;            // b*16 + h
    int h = bx & 15, b = bx >> 4;
    int tid = threadIdx.x;
    if (tid < 32) {
        float c = cost[2047 * 32 + tid], sn = sint[2047 * 32 + tid];
        float q0 = qlast[(size_t)b * E_ + h * 64 + 2 * tid];
        float q1 = qlast[(size_t)b * E_ + h * 64 + 2 * tid + 1];
        qr[2 * tid]     = q0 * c - q1 * sn;
        qr[2 * tid + 1] = q0 * sn + q1 * c;
    }
    __syncthreads();
    float best = -1e30f;
    for (int j = 0; j < 8; ++j) {
        int s = tid * 8 + j;
        const float* kr = &kf[((size_t)b * S_ + s) * E_ + h * 64];
        float acc = 0.f;
#pragma unroll
        for (int i = 0; i < 32; ++i) {
            float c = cost[s * 32 + i], sn = sint[s * 32 + i];
            float k0 = kr[2 * i], k1 = kr[2 * i + 1];
            acc += qr[2 * i] * (k0 * c - k1 * sn) + qr[2 * i + 1] * (k0 * sn + k1 * c);
        }
        best = fmaxf(best, acc);
    }
    lmax[tid] = best;
    __syncthreads();
    if (tid < 128) tmax[tid] = fmaxf(lmax[2 * tid], lmax[2 * tid + 1]);
    __syncthreads();
    if (tid == 0) {
        for (int t = 0; t < 8; ++t) {
            float bv = tmax[0]; int bi = 0;
            for (int i = 1; i < 128; ++i) {
                if (tmax[i] > bv) { bv = tmax[i]; bi = i; }
            }
            oidx[bx * 8 + t] = (float)bi;
            tmax[bi] = -3e30f;
        }
    }
}

// ---------------- launch ----------------
extern "C" void kernel_launch(void* const* d_in, const int* in_sizes, int n_in,
                              void* d_out, int out_size, void* d_ws, size_t ws_size,
                              hipStream_t stream) {
    (void)in_sizes; (void)n_in; (void)out_size; (void)ws_size;
    const float* x  = (const float*)d_in[0];
    const float* wq = (const float*)d_in[1];
    const float* wk = (const float*)d_in[2];
    const float* wv = (const float*)d_in[3];
    const float* wo = (const float*)d_in[4];
    float* out = (float*)d_out;

    char* wsp = (char*)d_ws;
    size_t off = 0;
    auto nxt = [&](size_t bytes) {
        char* p = wsp + off;
        off = (off + bytes + 255) & ~(size_t)255;
        return p;
    };
    u16* xb    = (u16*)nxt((size_t)BS_ * E_ * 2);
    u16* xlb   = (u16*)nxt((size_t)BS_ * E_ * 2);
    u16* wqt   = (u16*)nxt((size_t)E_ * E_ * 2);
    u16* wkt   = (u16*)nxt((size_t)E_ * E_ * 2);
    u16* wklt  = (u16*)nxt((size_t)E_ * E_ * 2);
    u16* wvt   = (u16*)nxt((size_t)E_ * E_ * 2);
    u16* wot   = (u16*)nxt((size_t)E_ * E_ * 2);
    float* qf  = (float*)nxt((size_t)BS_ * E_ * 4);
    float* kf  = (float*)nxt((size_t)BS_ * E_ * 4);
    float* vf  = (float*)nxt((size_t)BS_ * E_ * 4);
    float* cost = (float*)nxt((size_t)S_ * 32 * 4);
    float* sint = (float*)nxt((size_t)S_ * 32 * 4);
    u16* qb    = (u16*)nxt((size_t)B_ * H_ * S_ * D_ * 2);
    u16* kb    = (u16*)nxt((size_t)B_ * H_ * S_ * D_ * 2);
    u16* vtb   = (u16*)nxt((size_t)B_ * H_ * S_ * D_ * 2);
    u16* ab    = (u16*)nxt((size_t)BS_ * E_ * 2);
    float* qlast = (float*)nxt((size_t)B_ * E_ * 4);

    // prep
    hipLaunchKernelGGL(rope_table_kernel, dim3(S_ * 32 / 256), dim3(256), 0, stream, cost, sint);
    hipLaunchKernelGGL(convert_x_kernel, dim3(BS_ * E_ / 4 / 256), dim3(256), 0, stream, x, xb, xlb);
    hipLaunchKernelGGL(transpose_w_kernel, dim3(1024), dim3(256), 0, stream, wq, wqt, (u16*)nullptr);
    hipLaunchKernelGGL(transpose_w_kernel, dim3(1024), dim3(256), 0, stream, wk, wkt, wklt);
    hipLaunchKernelGGL(transpose_w_kernel, dim3(1024), dim3(256), 0, stream, wv, wvt, (u16*)nullptr);
    hipLaunchKernelGGL(transpose_w_kernel, dim3(1024), dim3(256), 0, stream, wo, wot, (u16*)nullptr);

    // projections (K gets 3-term split-precision for exact top-k ordering)
    dim3 ggrid(256);
    hipLaunchKernelGGL(gemm_bf16_kernel, ggrid, dim3(256), 0, stream, xb,  wqt,  qf, BS_, E_, E_, 0);
    hipLaunchKernelGGL(gemm_bf16_kernel, ggrid, dim3(256), 0, stream, xb,  wkt,  kf, BS_, E_, E_, 0);
    hipLaunchKernelGGL(gemm_bf16_kernel, ggrid, dim3(256), 0, stream, xlb, wkt,  kf, BS_, E_, E_, 1);
    hipLaunchKernelGGL(gemm_bf16_kernel, ggrid, dim3(256), 0, stream, xb,  wklt, kf, BS_, E_, E_, 1);
    hipLaunchKernelGGL(gemm_bf16_kernel, ggrid, dim3(256), 0, stream, xb,  wvt,  vf, BS_, E_, E_, 0);
    hipLaunchKernelGGL(qlast_kernel, dim3(B_ * E_ / 256), dim3(256), 0, stream, x, wq, qlast);

    // rearrange
    hipLaunchKernelGGL(rope_qk_kernel, dim3(B_ * S_ * H_ * 32 / 256), dim3(256), 0, stream,
                       qf, kf, cost, sint, qb, kb);
    hipLaunchKernelGGL(v_transpose_kernel, dim3(B_ * H_ * (S_ / 64)), dim3(256), 0, stream, vf, vtb);

    // attention + top-k
    hipLaunchKernelGGL(flash_kernel, dim3(B_ * H_ * (S_ / 64)), dim3(256), 0, stream, qb, kb, vtb, ab);
    hipLaunchKernelGGL(topk_kernel, dim3(B_ * H_), dim3(256), 0, stream,
                       qlast, kf, cost, sint, out + (size_t)BS_ * E_);

    // output projection
    hipLaunchKernelGGL(gemm_bf16_kernel, ggrid, dim3(256), 0, stream, ab, wot, out, BS_, E_, E_, 0);
}

// Round 2
// 520.058 us; speedup vs baseline: 1.2030x; 1.2030x over previous
//
#include <hip/hip_runtime.h>

#define B_ 2
#define S_ 2048
#define E_ 1024
#define H_ 16
#define D_ 64
#define BS_ (B_*S_)
#define PSTR 76   // flash P-lds stride in u16 (152B: 8B-aligned, ~2-way banks on read)

typedef unsigned short u16;
typedef __attribute__((ext_vector_type(8))) short short8;
typedef __attribute__((ext_vector_type(4))) float floatx4;
typedef __bf16 bf16x8 __attribute__((ext_vector_type(8)));

__device__ __forceinline__ u16 f2bf(float f) {
    unsigned int u = __builtin_bit_cast(unsigned int, f);
    u += 0x7FFFu + ((u >> 16) & 1u);
    return (u16)(u >> 16);
}
__device__ __forceinline__ float bf2f(u16 h) {
    return __builtin_bit_cast(float, (unsigned int)h << 16);
}
__device__ __forceinline__ floatx4 mfma16(short8 a, short8 b, floatx4 c) {
    return __builtin_amdgcn_mfma_f32_16x16x32_bf16(
        __builtin_bit_cast(bf16x8, a), __builtin_bit_cast(bf16x8, b), c, 0, 0, 0);
}
__device__ __forceinline__ void gload_lds16(const void* g, void* l) {
    __builtin_amdgcn_global_load_lds(
        (const __attribute__((address_space(1))) unsigned int*)g,
        (__attribute__((address_space(3))) unsigned int*)l, 16, 0, 0);
}

// ---------------- prep kernels ----------------

__global__ __launch_bounds__(256) void rope_table_kernel(float* __restrict__ cost,
                                                         float* __restrict__ sint) {
    int idx = blockIdx.x * 256 + threadIdx.x;   // S_*32
    int s = idx >> 5, i = idx & 31;
    float inv = powf(10000.0f, -(float)i / 32.0f);
    float a = (float)s * inv;
    cost[idx] = cosf(a);
    sint[idx] = sinf(a);
}

__global__ __launch_bounds__(256) void convert_x_kernel(const float* __restrict__ X,
                                                        u16* __restrict__ Xb,
                                                        u16* __restrict__ Xlb) {
    int i = blockIdx.x * 256 + threadIdx.x;     // BS_*E_/4 float4s
    float4 v = ((const float4*)X)[i];
    u16 h0 = f2bf(v.x), h1 = f2bf(v.y), h2 = f2bf(v.z), h3 = f2bf(v.w);
    uint2 o;
    o.x = (unsigned)h0 | ((unsigned)h1 << 16);
    o.y = (unsigned)h2 | ((unsigned)h3 << 16);
    ((uint2*)Xb)[i] = o;
    u16 l0 = f2bf(v.x - bf2f(h0)), l1 = f2bf(v.y - bf2f(h1));
    u16 l2 = f2bf(v.z - bf2f(h2)), l3 = f2bf(v.w - bf2f(h3));
    uint2 ol;
    ol.x = (unsigned)l0 | ((unsigned)l1 << 16);
    ol.y = (unsigned)l2 | ((unsigned)l3 << 16);
    ((uint2*)Xlb)[i] = ol;
}

// W [K][N] fp32 -> Wt [N][K] bf16 (+ optional residual)
__global__ __launch_bounds__(256) void transpose_w_kernel(const float* __restrict__ W,
                                                          u16* __restrict__ Wt,
                                                          u16* __restrict__ Wlt) {
    __shared__ float t[32][33];
    int ntn = E_ / 32;
    int bx = blockIdx.x;
    int tk = (bx / ntn) * 32, tn = (bx % ntn) * 32;
    int tx = threadIdx.x & 31, ty = threadIdx.x >> 5;   // 32 x 8
    for (int i = 0; i < 32; i += 8)
        t[ty + i][tx] = W[(size_t)(tk + ty + i) * E_ + tn + tx];
    __syncthreads();
    for (int i = 0; i < 32; i += 8) {
        float v = t[tx][ty + i];
        u16 hi = f2bf(v);
        Wt[(size_t)(tn + ty + i) * E_ + tk + tx] = hi;
        if (Wlt) Wlt[(size_t)(tn + ty + i) * E_ + tk + tx] = f2bf(v - bf2f(hi));
    }
}

// ---------------- GEMM core (128x128 tile, global_load_lds staging) ----------------

// stage one 128x64 bf16 tile (16KB) from src rows base row0, K-offset k0
__device__ __forceinline__ void stage_tile(const u16* __restrict__ src, int row0, int k0,
                                           int Kd, u16* lds, int tid) {
    int wv = tid >> 6, ln = tid & 63;
#pragma unroll
    for (int i = 0; i < 4; ++i) {
        int seg = i * 4 + wv;                 // 0..15
        int chunk = seg * 64 + ln;            // 0..1023
        int r = chunk >> 3;
        int c = (chunk & 7) * 8;
        gload_lds16(&src[(size_t)(row0 + r) * Kd + k0 + c],
                    (char*)lds + (size_t)seg * 1024);
    }
}

__device__ __forceinline__ void gemm_tile_body(const u16* lA, const u16* lB,
                                               floatx4 (*acc)[4], int lane, int wave) {
    int wm = (wave >> 1) * 64, wn = (wave & 1) * 64;
    int lr = lane & 15, lk = (lane >> 4) * 8;
#pragma unroll
    for (int kk = 0; kk < 64; kk += 32) {
        short8 afr[4], bfr[4];
#pragma unroll
        for (int mi = 0; mi < 4; ++mi)
            afr[mi] = *(const short8*)&lA[(wm + mi * 16 + lr) * 64 + kk + lk];
#pragma unroll
        for (int ni = 0; ni < 4; ++ni)
            bfr[ni] = *(const short8*)&lB[(wn + ni * 16 + lr) * 64 + kk + lk];
        __builtin_amdgcn_s_setprio(1);
#pragma unroll
        for (int mi = 0; mi < 4; ++mi)
#pragma unroll
            for (int ni = 0; ni < 4; ++ni)
                acc[mi][ni] = mfma16(afr[mi], bfr[ni], acc[mi][ni]);
        __builtin_amdgcn_s_setprio(0);
    }
}

__device__ __forceinline__ void gemm_write(float* __restrict__ C, floatx4 (*acc)[4],
                                           int m0, int n0, int N, int lane, int wave) {
    int wm = (wave >> 1) * 64, wn = (wave & 1) * 64;
    int lr = lane & 15, lq = lane >> 4;
#pragma unroll
    for (int mi = 0; mi < 4; ++mi)
#pragma unroll
        for (int ni = 0; ni < 4; ++ni)
#pragma unroll
            for (int r = 0; r < 4; ++r)
                C[(size_t)(m0 + wm + mi * 16 + lq * 4 + r) * N + n0 + wn + ni * 16 + lr]
                    = acc[mi][ni][r];
}

// fused QKV projection: grid 768 blocks (32 m x 24 strips), XCD-swizzled
__global__ __launch_bounds__(256) void qkv_gemm_kernel(const u16* __restrict__ xb,
                                                       const u16* __restrict__ xlb,
                                                       const u16* __restrict__ wqt,
                                                       const u16* __restrict__ wkt,
                                                       const u16* __restrict__ wklt,
                                                       const u16* __restrict__ wvt,
                                                       float* __restrict__ qf,
                                                       float* __restrict__ kf,
                                                       float* __restrict__ vf) {
    __shared__ __align__(16) u16 lA[128 * 64];
    __shared__ __align__(16) u16 lB[128 * 64];
    int bx = blockIdx.x;
    int lbx = (bx & 7) * 96 + (bx >> 3);      // bijective: 768 % 8 == 0
    int m0 = (lbx / 24) * 128;
    int strip = lbx % 24;
    int which = strip >> 3;
    int n0 = (strip & 7) * 128;
    int tid = threadIdx.x, lane = tid & 63, wave = tid >> 6;

    const u16* As[3]; const u16* Bs[3]; int np; float* out;
    if (which == 0)      { As[0] = xb;  Bs[0] = wqt; np = 1; out = qf; }
    else if (which == 1) { As[0] = xb;  Bs[0] = wkt; As[1] = xlb; Bs[1] = wkt;
                           As[2] = xb;  Bs[2] = wklt; np = 3; out = kf; }
    else                 { As[0] = xb;  Bs[0] = wvt; np = 1; out = vf; }

    floatx4 acc[4][4];
#pragma unroll
    for (int i = 0; i < 4; ++i)
#pragma unroll
        for (int j = 0; j < 4; ++j) acc[i][j] = (floatx4){0.f, 0.f, 0.f, 0.f};

    for (int p = 0; p < np; ++p) {
        const u16* A = As[p]; const u16* Bt = Bs[p];
        for (int k0 = 0; k0 < E_; k0 += 64) {
            stage_tile(A, m0, k0, E_, lA, tid);
            stage_tile(Bt, n0, k0, E_, lB, tid);
            __syncthreads();
            gemm_tile_body(lA, lB, acc, lane, wave);
            __syncthreads();
        }
    }
    gemm_write(out, acc, m0, n0, E_, lane, wave);
}

// plain GEMM: C[M][N] = A[M][K] @ Bt[N][K]^T   (grid (M/128)*(N/128), XCD-swizzled)
__global__ __launch_bounds__(256) void gemm_bf16_kernel(const u16* __restrict__ A,
                                                        const u16* __restrict__ Bt,
                                                        float* __restrict__ C,
                                                        int M, int N, int Kd) {
    __shared__ __align__(16) u16 lA[128 * 64];
    __shared__ __align__(16) u16 lB[128 * 64];
    int nwg = (M / 128) * (N / 128);
    int bx = blockIdx.x;
    int q = nwg >> 3, rr = nwg & 7, xcd = bx & 7, pos = bx >> 3;
    int lbx = (xcd < rr ? xcd * (q + 1) : rr * (q + 1) + (xcd - rr) * q) + pos;
    int nbn = N / 128;
    int m0 = (lbx / nbn) * 128, n0 = (lbx % nbn) * 128;
    int tid = threadIdx.x, lane = tid & 63, wave = tid >> 6;

    floatx4 acc[4][4];
#pragma unroll
    for (int i = 0; i < 4; ++i)
#pragma unroll
        for (int j = 0; j < 4; ++j) acc[i][j] = (floatx4){0.f, 0.f, 0.f, 0.f};

    for (int k0 = 0; k0 < Kd; k0 += 64) {
        stage_tile(A, m0, k0, Kd, lA, tid);
        stage_tile(Bt, n0, k0, Kd, lB, tid);
        __syncthreads();
        gemm_tile_body(lA, lB, acc, lane, wave);
        __syncthreads();
    }
    gemm_write(C, acc, m0, n0, N, lane, wave);
}

// ---------------- fp32 q for the last token (exact path for top-k) ----------------
__global__ __launch_bounds__(256) void qlast_kernel(const float* __restrict__ x,
                                                    const float* __restrict__ wq,
                                                    float* __restrict__ qlast) {
    // 64 blocks: b = bx>>5, cols (bx&31)*32..+32; tid: col = tid&31, kchunk = tid>>5
    __shared__ float red[8][32];
    int bx = blockIdx.x;
    int b = bx >> 5, c0 = (bx & 31) * 32;
    int cl = threadIdx.x & 31, kc = threadIdx.x >> 5;
    const float* xr = &x[((size_t)b * S_ + (S_ - 1)) * E_ + kc * 128];
    const float* wp = &wq[(size_t)(kc * 128) * E_ + c0 + cl];
    float acc = 0.f;
#pragma unroll 4
    for (int e = 0; e < 128; ++e) acc = fmaf(xr[e], wp[(size_t)e * E_], acc);
    red[kc][cl] = acc;
    __syncthreads();
    if (kc == 0) {
        float s = ((red[0][cl] + red[1][cl]) + (red[2][cl] + red[3][cl]))
                + ((red[4][cl] + red[5][cl]) + (red[6][cl] + red[7][cl]));
        qlast[(size_t)b * E_ + c0 + cl] = s;
    }
}

// ---------------- RoPE + rearrange q,k to [b][h][s][d] bf16 ----------------
__global__ __launch_bounds__(256) void rope_qk_kernel(const float* __restrict__ qf,
                                                      const float* __restrict__ kf,
                                                      const float* __restrict__ cost,
                                                      const float* __restrict__ sint,
                                                      u16* __restrict__ qb,
                                                      u16* __restrict__ kb) {
    int idx = blockIdx.x * 256 + threadIdx.x;   // B_*S_*H_*32 = 2^21
    int i = idx & 31;
    int h = (idx >> 5) & 15;
    int s = (idx >> 9) & 2047;
    int b = idx >> 20;
    float c = cost[s * 32 + i], sn = sint[s * 32 + i];
    size_t src = ((size_t)b * S_ + s) * E_ + h * 64 + 2 * i;
    float q0 = qf[src], q1 = qf[src + 1];
    float k0 = kf[src], k1 = kf[src + 1];
    size_t dst = (((size_t)(b * H_ + h) * S_) + s) * D_ + 2 * i;
    unsigned qo = (unsigned)f2bf(q0 * c - q1 * sn) | ((unsigned)f2bf(q0 * sn + q1 * c) << 16);
    unsigned ko = (unsigned)f2bf(k0 * c - k1 * sn) | ((unsigned)f2bf(k0 * sn + k1 * c) << 16);
    *(unsigned*)&qb[dst] = qo;
    *(unsigned*)&kb[dst] = ko;
}

// ---------------- V -> vtb [b][h][d][s] bf16 (LDS-tiled transpose) ----------------
__global__ __launch_bounds__(256) void v_transpose_kernel(const float* __restrict__ vf,
                                                          u16* __restrict__ vtb) {
    __shared__ float t[64][65];
    int bx = blockIdx.x;            // b*512 + h*32 + sc
    int sc = bx & 31;
    int h = (bx >> 5) & 15;
    int b = bx >> 9;
    int s0 = sc * 64;
    int tid = threadIdx.x;
    int d = tid & 63, sr = tid >> 6;
    for (int j = 0; j < 64; j += 4)
        t[sr + j][d] = vf[((size_t)b * S_ + s0 + sr + j) * E_ + h * 64 + d];
    __syncthreads();
    int sj = tid & 63, dr = tid >> 6;
    for (int j = 0; j < 64; j += 4)
        vtb[(((size_t)(b * H_ + h)) * D_ + dr + j) * S_ + s0 + sj] = f2bf(t[sj][dr + j]);
}

// ---------------- flash attention: swapped QK^T, KVBLK=64, lane-local softmax ----------------
__global__ __launch_bounds__(256) void flash_kernel(const u16* __restrict__ qb,
                                                    const u16* __restrict__ kb,
                                                    const u16* __restrict__ vtb,
                                                    u16* __restrict__ ab) {
    __shared__ __align__(16) u16 ldsP[4][16 * PSTR];   // per-wave P[q=16][k=64], padded
    int tid = threadIdx.x;
    int lane = tid & 63, wave = tid >> 6;
    int bx = blockIdx.x;            // b*512 + h*32 + qcslot
    int qc = 31 - (bx & 31);        // reversed: longest q-tiles dispatch first
    int h = (bx >> 5) & 15, b = bx >> 9;
    int qt0 = qc * 64 + wave * 16;
    size_t bh = (size_t)(b * H_ + h);
    const u16* Q = qb + bh * S_ * D_;
    const u16* K = kb + bh * S_ * D_;
    const u16* V = vtb + bh * D_ * S_;
    u16* lp = &ldsP[wave][0];
    int lr = lane & 15, lq = lane >> 4, lk = lq * 8;

    short8 qfr0 = *(const short8*)&Q[(size_t)(qt0 + lr) * D_ + lk];
    short8 qfr1 = *(const short8*)&Q[(size_t)(qt0 + lr) * D_ + 32 + lk];

    floatx4 o0 = {0,0,0,0}, o1 = {0,0,0,0}, o2 = {0,0,0,0}, o3 = {0,0,0,0};
    float m = -1e30f, l = 0.f;          // running stats for q = qt0 + lr
    int nend = qt0 + 16;
    for (int n0 = 0; n0 < nend; n0 += 64) {
        int rem = nend - n0;            // multiple of 16
        int kt_end = rem >= 64 ? 4 : (rem >> 4);
        // --- QK^T swapped: st[kt] holds S^T[k=n0+kt*16+lq*4+r][q=qt0+lr]
        floatx4 st[4];
#pragma unroll
        for (int kt = 0; kt < 4; ++kt) st[kt] = (floatx4){0.f, 0.f, 0.f, 0.f};
        __builtin_amdgcn_s_setprio(1);
#pragma unroll
        for (int kt = 0; kt < 4; ++kt) {
            if (kt < kt_end) {
                const u16* Kr = &K[(size_t)(n0 + kt * 16 + lr) * D_];
                st[kt] = mfma16(*(const short8*)&Kr[lk], qfr0, st[kt]);
                st[kt] = mfma16(*(const short8*)&Kr[32 + lk], qfr1, st[kt]);
            }
        }
        __builtin_amdgcn_s_setprio(0);
        // --- mask + scale
        float sv[4][4];
        float bmax = -1e30f;
        if (rem >= 80) {                // interior: no mask needed (q >= n0+64 for all lanes)
#pragma unroll
            for (int kt = 0; kt < 4; ++kt)
#pragma unroll
                for (int r = 0; r < 4; ++r) {
                    float s = st[kt][r] * 0.125f;
                    sv[kt][r] = s;
                    bmax = fmaxf(bmax, s);
                }
        } else {
#pragma unroll
            for (int kt = 0; kt < 4; ++kt)
#pragma unroll
                for (int r = 0; r < 4; ++r) {
                    int k = n0 + kt * 16 + lq * 4 + r;
                    float s = (kt < kt_end && k <= qt0 + lr) ? st[kt][r] * 0.125f : -1e30f;
                    sv[kt][r] = s;
                    bmax = fmaxf(bmax, s);
                }
        }
        // --- row stats (row = q = lr, spread over lq groups)
        bmax = fmaxf(bmax, __shfl_xor(bmax, 16));
        bmax = fmaxf(bmax, __shfl_xor(bmax, 32));
        float mn = fmaxf(m, bmax);
        float alpha = __expf(m - mn);
        m = mn;
        float ps = 0.f;
        float pv[4][4];
#pragma unroll
        for (int kt = 0; kt < 4; ++kt)
#pragma unroll
            for (int r = 0; r < 4; ++r) {
                float p = __expf(sv[kt][r] - mn);
                pv[kt][r] = p;
                ps += p;
            }
        // pack P^T -> LDS as P[q][k] (4 consecutive k per 8B write)
#pragma unroll
        for (int kt = 0; kt < 4; ++kt) {
            uint2 w;
            w.x = (unsigned)f2bf(pv[kt][0]) | ((unsigned)f2bf(pv[kt][1]) << 16);
            w.y = (unsigned)f2bf(pv[kt][2]) | ((unsigned)f2bf(pv[kt][3]) << 16);
            *(uint2*)&lp[lr * PSTR + kt * 16 + lq * 4] = w;
        }
        ps += __shfl_xor(ps, 16);
        ps += __shfl_xor(ps, 32);
        l = l * alpha + ps;
        // --- rescale O (O rows are q = lq*4+r; alpha lives at lane q)
        float af[4];
#pragma unroll
        for (int r = 0; r < 4; ++r) af[r] = __shfl(alpha, lq * 4 + r);
#pragma unroll
        for (int r = 0; r < 4; ++r) {
            o0[r] *= af[r]; o1[r] *= af[r]; o2[r] *= af[r]; o3[r] *= af[r];
        }
        asm volatile("s_waitcnt lgkmcnt(0)" ::: "memory");
        // --- PV: O[q][d] += P[q][k] * Vt[d][k]
        int cend = (kt_end + 1) >> 1;
        __builtin_amdgcn_s_setprio(1);
#pragma unroll
        for (int c = 0; c < 2; ++c) {
            if (c < cend) {
                uint2 plo = *(const uint2*)&lp[lr * PSTR + c * 32 + lk];
                uint2 phi = *(const uint2*)&lp[lr * PSTR + c * 32 + lk + 4];
                short8 pfr = __builtin_bit_cast(short8, (uint4){plo.x, plo.y, phi.x, phi.y});
                const u16* Vb = &V[(size_t)lr * S_ + n0 + c * 32 + lk];
                o0 = mfma16(pfr, *(const short8*)&Vb[0 * 16 * S_], o0);
                o1 = mfma16(pfr, *(const short8*)&Vb[1 * 16 * S_], o1);
                o2 = mfma16(pfr, *(const short8*)&Vb[2 * 16 * S_], o2);
                o3 = mfma16(pfr, *(const short8*)&Vb[3 * 16 * S_], o3);
            }
        }
        __builtin_amdgcn_s_setprio(0);
    }
    float li[4];
#pragma unroll
    for (int r = 0; r < 4; ++r) li[r] = 1.0f / __shfl(l, lq * 4 + r);
    size_t orow_base = ((size_t)b * S_ + qt0 + lq * 4) * E_ + h * D_;
#pragma unroll
    for (int r = 0; r < 4; ++r) {
        size_t rb = orow_base + (size_t)r * E_;
        ab[rb + 0  + lr] = f2bf(o0[r] * li[r]);
        ab[rb + 16 + lr] = f2bf(o1[r] * li[r]);
        ab[rb + 32 + lr] = f2bf(o2[r] * li[r]);
        ab[rb + 48 + lr] = f2bf(o3[r] * li[r]);
    }
}

// ---------------- top-8 tiles from last-row logits (fp32 path) ----------------
__global__ __launch_bounds__(256) void topk_kernel(const float* __restrict__ qlast,
                                                   const float* __restrict__ kf,
                                                   const float* __restrict__ cost,
                                                   const float* __restrict__ sint,
                                                   float* __restrict__ oidx) {
    __shared__ float qr[64];
    __shared__ float lmax[256];
    __shared__ float tmax[128];
    int bx = blockIdx.x;            // b*16 + h
    int h = bx & 15, b = bx >> 4;
    int tid = threadIdx.x;
    if (tid < 32) {
        float c = cost[2047 * 32 + tid], sn = sint[2047 * 32 + tid];
        float q0 = qlast[(size_t)b * E_ + h * 64 + 2 * tid];
        float q1 = qlast[(size_t)b * E_ + h * 64 + 2 * tid + 1];
        qr[2 * tid]     = q0 * c - q1 * sn;
        qr[2 * tid + 1] = q0 * sn + q1 * c;
    }
    __syncthreads();
    float best = -1e30f;
    for (int j = 0; j < 8; ++j) {
        int s = tid * 8 + j;
        const float* kr = &kf[((size_t)b * S_ + s) * E_ + h * 64];
        float acc = 0.f;
#pragma unroll
        for (int i = 0; i < 32; ++i) {
            float c = cost[s * 32 + i], sn = sint[s * 32 + i];
            float k0 = kr[2 * i], k1 = kr[2 * i + 1];
            acc += qr[2 * i] * (k0 * c - k1 * sn) + qr[2 * i + 1] * (k0 * sn + k1 * c);
        }
        best = fmaxf(best, acc);
    }
    lmax[tid] = best;
    __syncthreads();
    if (tid < 128) tmax[tid] = fmaxf(lmax[2 * tid], lmax[2 * tid + 1]);
    __syncthreads();
    if (tid < 64) {                  // wave-parallel top-8 with lowest-index tiebreak
        float v0 = tmax[tid], v1 = tmax[tid + 64];
        float va, vb; int ia, ib;
        if (v1 > v0) { va = v1; ia = tid + 64; vb = v0; ib = tid; }
        else         { va = v0; ia = tid;      vb = v1; ib = tid + 64; }
        float cv = va; int ci = ia; int used = 0;
        for (int t = 0; t < 8; ++t) {
            float bv = cv; int bi = ci;
#pragma unroll
            for (int mk = 1; mk < 64; mk <<= 1) {
                float ov = __shfl_xor(bv, mk);
                int oi = __shfl_xor(bi, mk);
                if (ov > bv || (ov == bv && oi < bi)) { bv = ov; bi = oi; }
            }
            if (tid == 0) oidx[bx * 8 + t] = (float)bi;
            if (ci == bi) {
                if (used == 0) { cv = vb; ci = ib; used = 1; }
                else           { cv = -3e30f; ci = 1 << 20; }
            }
        }
    }
}

// ---------------- launch ----------------
extern "C" void kernel_launch(void* const* d_in, const int* in_sizes, int n_in,
                              void* d_out, int out_size, void* d_ws, size_t ws_size,
                              hipStream_t stream) {
    (void)in_sizes; (void)n_in; (void)out_size; (void)ws_size;
    const float* x  = (const float*)d_in[0];
    const float* wq = (const float*)d_in[1];
    const float* wk = (const float*)d_in[2];
    const float* wv = (const float*)d_in[3];
    const float* wo = (const float*)d_in[4];
    float* out = (float*)d_out;

    char* wsp = (char*)d_ws;
    size_t off = 0;
    auto nxt = [&](size_t bytes) {
        char* p = wsp + off;
        off = (off + bytes + 255) & ~(size_t)255;
        return p;
    };
    u16* xb    = (u16*)nxt((size_t)BS_ * E_ * 2);
    u16* xlb   = (u16*)nxt((size_t)BS_ * E_ * 2);
    u16* wqt   = (u16*)nxt((size_t)E_ * E_ * 2);
    u16* wkt   = (u16*)nxt((size_t)E_ * E_ * 2);
    u16* wklt  = (u16*)nxt((size_t)E_ * E_ * 2);
    u16* wvt   = (u16*)nxt((size_t)E_ * E_ * 2);
    u16* wot   = (u16*)nxt((size_t)E_ * E_ * 2);
    float* qf  = (float*)nxt((size_t)BS_ * E_ * 4);
    float* kf  = (float*)nxt((size_t)BS_ * E_ * 4);
    float* vf  = (float*)nxt((size_t)BS_ * E_ * 4);
    float* cost = (float*)nxt((size_t)S_ * 32 * 4);
    float* sint = (float*)nxt((size_t)S_ * 32 * 4);
    u16* qb    = (u16*)nxt((size_t)B_ * H_ * S_ * D_ * 2);
    u16* kb    = (u16*)nxt((size_t)B_ * H_ * S_ * D_ * 2);
    u16* vtb   = (u16*)nxt((size_t)B_ * H_ * S_ * D_ * 2);
    u16* ab    = (u16*)nxt((size_t)BS_ * E_ * 2);
    float* qlast = (float*)nxt((size_t)B_ * E_ * 4);

    // prep
    hipLaunchKernelGGL(rope_table_kernel, dim3(S_ * 32 / 256), dim3(256), 0, stream, cost, sint);
    hipLaunchKernelGGL(convert_x_kernel, dim3(BS_ * E_ / 4 / 256), dim3(256), 0, stream, x, xb, xlb);
    hipLaunchKernelGGL(transpose_w_kernel, dim3(1024), dim3(256), 0, stream, wq, wqt, (u16*)nullptr);
    hipLaunchKernelGGL(transpose_w_kernel, dim3(1024), dim3(256), 0, stream, wk, wkt, wklt);
    hipLaunchKernelGGL(transpose_w_kernel, dim3(1024), dim3(256), 0, stream, wv, wvt, (u16*)nullptr);
    hipLaunchKernelGGL(transpose_w_kernel, dim3(1024), dim3(256), 0, stream, wo, wot, (u16*)nullptr);

    // fused QKV projections (K gets 3-term split-precision, accumulated in-register)
    hipLaunchKernelGGL(qkv_gemm_kernel, dim3(768), dim3(256), 0, stream,
                       xb, xlb, wqt, wkt, wklt, wvt, qf, kf, vf);
    hipLaunchKernelGGL(qlast_kernel, dim3(64), dim3(256), 0, stream, x, wq, qlast);

    // rearrange
    hipLaunchKernelGGL(rope_qk_kernel, dim3(B_ * S_ * H_ * 32 / 256), dim3(256), 0, stream,
                       qf, kf, cost, sint, qb, kb);
    hipLaunchKernelGGL(v_transpose_kernel, dim3(B_ * H_ * (S_ / 64)), dim3(256), 0, stream, vf, vtb);

    // attention + top-k
    hipLaunchKernelGGL(flash_kernel, dim3(B_ * H_ * (S_ / 64)), dim3(256), 0, stream, qb, kb, vtb, ab);
    hipLaunchKernelGGL(topk_kernel, dim3(B_ * H_), dim3(256), 0, stream,
                       qlast, kf, cost, sint, out + (size_t)BS_ * E_);

    // output projection
    hipLaunchKernelGGL(gemm_bf16_kernel, dim3(256), dim3(256), 0, stream, ab, wot, out,
                       BS_, E_, E_);
}

// Round 3
// 477.745 us; speedup vs baseline: 1.3096x; 1.0886x over previous
//
#include <hip/hip_runtime.h>

#define B_ 2
#define S_ 2048
#define E_ 1024
#define H_ 16
#define D_ 64
#define BS_ (B_*S_)
#define PSTR 76   // flash P-lds stride in u16

typedef unsigned short u16;
typedef __attribute__((ext_vector_type(8))) short short8;
typedef __attribute__((ext_vector_type(4))) float floatx4;
typedef __bf16 bf16x8 __attribute__((ext_vector_type(8)));

__device__ __forceinline__ u16 f2bf(float f) {
    unsigned int u = __builtin_bit_cast(unsigned int, f);
    u += 0x7FFFu + ((u >> 16) & 1u);
    return (u16)(u >> 16);
}
__device__ __forceinline__ float bf2f(u16 h) {
    return __builtin_bit_cast(float, (unsigned int)h << 16);
}
__device__ __forceinline__ floatx4 mfma16(short8 a, short8 b, floatx4 c) {
    return __builtin_amdgcn_mfma_f32_16x16x32_bf16(
        __builtin_bit_cast(bf16x8, a), __builtin_bit_cast(bf16x8, b), c, 0, 0, 0);
}
__device__ __forceinline__ void gload_lds16(const void* g, void* l) {
    __builtin_amdgcn_global_load_lds(
        (const __attribute__((address_space(1))) unsigned int*)g,
        (__attribute__((address_space(3))) unsigned int*)l, 16, 0, 0);
}

// ---------------- prep kernels ----------------

__global__ __launch_bounds__(256) void rope_table_kernel(float* __restrict__ cost,
                                                         float* __restrict__ sint) {
    int idx = blockIdx.x * 256 + threadIdx.x;   // S_*32
    int s = idx >> 5, i = idx & 31;
    float inv = powf(10000.0f, -(float)i / 32.0f);
    float a = (float)s * inv;
    cost[idx] = cosf(a);
    sint[idx] = sinf(a);
}

__global__ __launch_bounds__(256) void convert_x_kernel(const float* __restrict__ X,
                                                        u16* __restrict__ Xb,
                                                        u16* __restrict__ Xlb) {
    int i = blockIdx.x * 256 + threadIdx.x;     // BS_*E_/4 float4s
    float4 v = ((const float4*)X)[i];
    u16 h0 = f2bf(v.x), h1 = f2bf(v.y), h2 = f2bf(v.z), h3 = f2bf(v.w);
    uint2 o;
    o.x = (unsigned)h0 | ((unsigned)h1 << 16);
    o.y = (unsigned)h2 | ((unsigned)h3 << 16);
    ((uint2*)Xb)[i] = o;
    u16 l0 = f2bf(v.x - bf2f(h0)), l1 = f2bf(v.y - bf2f(h1));
    u16 l2 = f2bf(v.z - bf2f(h2)), l3 = f2bf(v.w - bf2f(h3));
    uint2 ol;
    ol.x = (unsigned)l0 | ((unsigned)l1 << 16);
    ol.y = (unsigned)l2 | ((unsigned)l3 << 16);
    ((uint2*)Xlb)[i] = ol;
}

// W [K][N] fp32 -> Wt [N][K] bf16 (+ optional residual)
__global__ __launch_bounds__(256) void transpose_w_kernel(const float* __restrict__ W,
                                                          u16* __restrict__ Wt,
                                                          u16* __restrict__ Wlt) {
    __shared__ float t[32][33];
    int ntn = E_ / 32;
    int bx = blockIdx.x;
    int tk = (bx / ntn) * 32, tn = (bx % ntn) * 32;
    int tx = threadIdx.x & 31, ty = threadIdx.x >> 5;   // 32 x 8
    for (int i = 0; i < 32; i += 8)
        t[ty + i][tx] = W[(size_t)(tk + ty + i) * E_ + tn + tx];
    __syncthreads();
    for (int i = 0; i < 32; i += 8) {
        float v = t[tx][ty + i];
        u16 hi = f2bf(v);
        Wt[(size_t)(tn + ty + i) * E_ + tk + tx] = hi;
        if (Wlt) Wlt[(size_t)(tn + ty + i) * E_ + tk + tx] = f2bf(v - bf2f(hi));
    }
}

// ---------------- GEMM core (128x128 tile, global_load_lds staging) ----------------

__device__ __forceinline__ void stage_tile(const u16* __restrict__ src, int row0, int k0,
                                           int Kd, u16* lds, int tid) {
    int wv = tid >> 6, ln = tid & 63;
#pragma unroll
    for (int i = 0; i < 4; ++i) {
        int seg = i * 4 + wv;                 // 0..15
        int chunk = seg * 64 + ln;            // 0..1023
        int r = chunk >> 3;
        int c = (chunk & 7) * 8;
        gload_lds16(&src[(size_t)(row0 + r) * Kd + k0 + c],
                    (char*)lds + (size_t)seg * 1024);
    }
}

__device__ __forceinline__ void gemm_tile_body(const u16* lA, const u16* lB,
                                               floatx4 (*acc)[4], int lane, int wave) {
    int wm = (wave >> 1) * 64, wn = (wave & 1) * 64;
    int lr = lane & 15, lk = (lane >> 4) * 8;
#pragma unroll
    for (int kk = 0; kk < 64; kk += 32) {
        short8 afr[4], bfr[4];
#pragma unroll
        for (int mi = 0; mi < 4; ++mi)
            afr[mi] = *(const short8*)&lA[(wm + mi * 16 + lr) * 64 + kk + lk];
#pragma unroll
        for (int ni = 0; ni < 4; ++ni)
            bfr[ni] = *(const short8*)&lB[(wn + ni * 16 + lr) * 64 + kk + lk];
        __builtin_amdgcn_s_setprio(1);
#pragma unroll
        for (int mi = 0; mi < 4; ++mi)
#pragma unroll
            for (int ni = 0; ni < 4; ++ni)
                acc[mi][ni] = mfma16(afr[mi], bfr[ni], acc[mi][ni]);
        __builtin_amdgcn_s_setprio(0);
    }
}

__device__ __forceinline__ void gemm_write(float* __restrict__ C, floatx4 (*acc)[4],
                                           int m0, int n0, int N, int lane, int wave) {
    int wm = (wave >> 1) * 64, wn = (wave & 1) * 64;
    int lr = lane & 15, lq = lane >> 4;
#pragma unroll
    for (int mi = 0; mi < 4; ++mi)
#pragma unroll
        for (int ni = 0; ni < 4; ++ni)
#pragma unroll
            for (int r = 0; r < 4; ++r)
                C[(size_t)(m0 + wm + mi * 16 + lq * 4 + r) * N + n0 + wn + ni * 16 + lr]
                    = acc[mi][ni][r];
}

// uniform 5-pass projection GEMM: grid 1280, XCD-swizzled, one term per block
__global__ __launch_bounds__(256) void proj_gemm_kernel(const u16* __restrict__ xb,
                                                        const u16* __restrict__ xlb,
                                                        const u16* __restrict__ wqt,
                                                        const u16* __restrict__ wkt,
                                                        const u16* __restrict__ wklt,
                                                        const u16* __restrict__ wvt,
                                                        float* __restrict__ qf,
                                                        float* __restrict__ kf,
                                                        float* __restrict__ kfl1,
                                                        float* __restrict__ kfl2,
                                                        float* __restrict__ vf) {
    __shared__ __align__(16) u16 lA[128 * 64];
    __shared__ __align__(16) u16 lB[128 * 64];
    int bx = blockIdx.x;
    int lbx = (bx & 7) * 160 + (bx >> 3);     // bijective: 1280 % 8 == 0
    int pass = lbx % 5;
    int idx = lbx / 5;
    int m0 = (idx >> 3) * 128, n0 = (idx & 7) * 128;
    int tid = threadIdx.x, lane = tid & 63, wave = tid >> 6;

    const u16* A  = (pass == 2) ? xlb : xb;
    const u16* Bt = (pass == 0) ? wqt : (pass == 3) ? wklt : (pass == 4) ? wvt : wkt;
    float* out = (pass == 0) ? qf : (pass == 1) ? kf : (pass == 2) ? kfl1
               : (pass == 3) ? kfl2 : vf;

    floatx4 acc[4][4];
#pragma unroll
    for (int i = 0; i < 4; ++i)
#pragma unroll
        for (int j = 0; j < 4; ++j) acc[i][j] = (floatx4){0.f, 0.f, 0.f, 0.f};

    for (int k0 = 0; k0 < E_; k0 += 64) {
        stage_tile(A, m0, k0, E_, lA, tid);
        stage_tile(Bt, n0, k0, E_, lB, tid);
        __syncthreads();
        gemm_tile_body(lA, lB, acc, lane, wave);
        __syncthreads();
    }
    gemm_write(out, acc, m0, n0, E_, lane, wave);
}

// plain GEMM (for the output projection)
__global__ __launch_bounds__(256) void gemm_bf16_kernel(const u16* __restrict__ A,
                                                        const u16* __restrict__ Bt,
                                                        float* __restrict__ C,
                                                        int M, int N, int Kd) {
    __shared__ __align__(16) u16 lA[128 * 64];
    __shared__ __align__(16) u16 lB[128 * 64];
    int nwg = (M / 128) * (N / 128);
    int bx = blockIdx.x;
    int q = nwg >> 3, rr = nwg & 7, xcd = bx & 7, pos = bx >> 3;
    int lbx = (xcd < rr ? xcd * (q + 1) : rr * (q + 1) + (xcd - rr) * q) + pos;
    int nbn = N / 128;
    int m0 = (lbx / nbn) * 128, n0 = (lbx % nbn) * 128;
    int tid = threadIdx.x, lane = tid & 63, wave = tid >> 6;

    floatx4 acc[4][4];
#pragma unroll
    for (int i = 0; i < 4; ++i)
#pragma unroll
        for (int j = 0; j < 4; ++j) acc[i][j] = (floatx4){0.f, 0.f, 0.f, 0.f};

    for (int k0 = 0; k0 < Kd; k0 += 64) {
        stage_tile(A, m0, k0, Kd, lA, tid);
        stage_tile(Bt, n0, k0, Kd, lB, tid);
        __syncthreads();
        gemm_tile_body(lA, lB, acc, lane, wave);
        __syncthreads();
    }
    gemm_write(C, acc, m0, n0, N, lane, wave);
}

// ---------------- fp32 q for the last token (exact path for top-k) ----------------
__global__ __launch_bounds__(256) void qlast_kernel(const float* __restrict__ x,
                                                    const float* __restrict__ wq,
                                                    float* __restrict__ qlast) {
    __shared__ float red[8][32];
    int bx = blockIdx.x;
    int b = bx >> 5, c0 = (bx & 31) * 32;
    int cl = threadIdx.x & 31, kc = threadIdx.x >> 5;
    const float* xr = &x[((size_t)b * S_ + (S_ - 1)) * E_ + kc * 128];
    const float* wp = &wq[(size_t)(kc * 128) * E_ + c0 + cl];
    float acc = 0.f;
#pragma unroll 4
    for (int e = 0; e < 128; ++e) acc = fmaf(xr[e], wp[(size_t)e * E_], acc);
    red[kc][cl] = acc;
    __syncthreads();
    if (kc == 0) {
        float s = ((red[0][cl] + red[1][cl]) + (red[2][cl] + red[3][cl]))
                + ((red[4][cl] + red[5][cl]) + (red[6][cl] + red[7][cl]));
        qlast[(size_t)b * E_ + c0 + cl] = s;
    }
}

// ---------------- RoPE + rearrange q,k to [b][h][s][d] bf16 ----------------
__global__ __launch_bounds__(256) void rope_qk_kernel(const float* __restrict__ qf,
                                                      const float* __restrict__ kf,
                                                      const float* __restrict__ kfl1,
                                                      const float* __restrict__ kfl2,
                                                      const float* __restrict__ cost,
                                                      const float* __restrict__ sint,
                                                      u16* __restrict__ qb,
                                                      u16* __restrict__ kb) {
    int idx = blockIdx.x * 256 + threadIdx.x;   // B_*S_*H_*32 = 2^21
    int i = idx & 31;
    int h = (idx >> 5) & 15;
    int s = (idx >> 9) & 2047;
    int b = idx >> 20;
    float c = cost[s * 32 + i], sn = sint[s * 32 + i];
    size_t src = ((size_t)b * S_ + s) * E_ + h * 64 + 2 * i;
    float q0 = qf[src], q1 = qf[src + 1];
    float k0 = (kf[src] + kfl1[src]) + kfl2[src];
    float k1 = (kf[src + 1] + kfl1[src + 1]) + kfl2[src + 1];
    size_t dst = (((size_t)(b * H_ + h) * S_) + s) * D_ + 2 * i;
    unsigned qo = (unsigned)f2bf(q0 * c - q1 * sn) | ((unsigned)f2bf(q0 * sn + q1 * c) << 16);
    unsigned ko = (unsigned)f2bf(k0 * c - k1 * sn) | ((unsigned)f2bf(k0 * sn + k1 * c) << 16);
    *(unsigned*)&qb[dst] = qo;
    *(unsigned*)&kb[dst] = ko;
}

// ---------------- V -> vtb [b][h][d][s] bf16 (LDS-tiled transpose) ----------------
__global__ __launch_bounds__(256) void v_transpose_kernel(const float* __restrict__ vf,
                                                          u16* __restrict__ vtb) {
    __shared__ float t[64][65];
    int bx = blockIdx.x;            // b*512 + h*32 + sc
    int sc = bx & 31;
    int h = (bx >> 5) & 15;
    int b = bx >> 9;
    int s0 = sc * 64;
    int tid = threadIdx.x;
    int d = tid & 63, sr = tid >> 6;
    for (int j = 0; j < 64; j += 4)
        t[sr + j][d] = vf[((size_t)b * S_ + s0 + sr + j) * E_ + h * 64 + d];
    __syncthreads();
    int sj = tid & 63, dr = tid >> 6;
    for (int j = 0; j < 64; j += 4)
        vtb[(((size_t)(b * H_ + h)) * D_ + dr + j) * S_ + s0 + sj] = f2bf(t[sj][dr + j]);
}

// ---------------- flash attention: swapped QK^T, software-pipelined K/V ----------------
__global__ __launch_bounds__(256) void flash_kernel(const u16* __restrict__ qb,
                                                    const u16* __restrict__ kb,
                                                    const u16* __restrict__ vtb,
                                                    u16* __restrict__ ab) {
    __shared__ __align__(16) u16 ldsP[4][16 * PSTR];   // per-wave P[q=16][k=64]
    int tid = threadIdx.x;
    int lane = tid & 63, wave = tid >> 6;
    int bx = blockIdx.x;
    int xcd = bx & 7, ii = bx >> 3;
    int hid = xcd + 8 * (ii & 3);   // 4 heads per XCD -> K/V L2-resident (2MB/XCD)
    int qc = 31 - (ii >> 2);        // longest q-chunks dispatch first
    int qt0 = qc * 64 + wave * 16;
    const u16* Q = qb + (size_t)hid * S_ * D_;
    const u16* K = kb + (size_t)hid * S_ * D_;
    const u16* V = vtb + (size_t)hid * D_ * S_;
    u16* lp = &ldsP[wave][0];
    int lr = lane & 15, lq = lane >> 4, lk = lq * 8;

    short8 qfr0 = *(const short8*)&Q[(size_t)(qt0 + lr) * D_ + lk];
    short8 qfr1 = *(const short8*)&Q[(size_t)(qt0 + lr) * D_ + 32 + lk];

    floatx4 o0 = {0,0,0,0}, o1 = {0,0,0,0}, o2 = {0,0,0,0}, o3 = {0,0,0,0};
    float m = -1e30f, l = 0.f;      // running stats (base-2 domain) for q = qt0 + lr
    int nend = qt0 + 16;

    // prefetch K tile 0 into registers
    short8 ka0[4], ka1[4];
#pragma unroll
    for (int kt = 0; kt < 4; ++kt) {
        const u16* Kr = &K[(size_t)(kt * 16 + lr) * D_];
        ka0[kt] = *(const short8*)&Kr[lk];
        ka1[kt] = *(const short8*)&Kr[32 + lk];
    }

    for (int n0 = 0; n0 < nend; n0 += 64) {
        int rem = nend - n0;
        int npre = (n0 + 64 < nend) ? n0 + 64 : n0;
        // issue current V loads (consumed at iteration end)
        short8 vv[2][4];
#pragma unroll
        for (int c = 0; c < 2; ++c)
#pragma unroll
            for (int o = 0; o < 4; ++o)
                vv[c][o] = *(const short8*)&V[(size_t)(o * 16 + lr) * S_ + n0 + c * 32 + lk];
        // issue next-iteration K loads
        short8 kn0[4], kn1[4];
#pragma unroll
        for (int kt = 0; kt < 4; ++kt) {
            const u16* Kr = &K[(size_t)(npre + kt * 16 + lr) * D_];
            kn0[kt] = *(const short8*)&Kr[lk];
            kn1[kt] = *(const short8*)&Kr[32 + lk];
        }
        // QK^T swapped: st[kt][r] = S^T[k=n0+kt*16+lq*4+r][q=qt0+lr]
        floatx4 st[4];
#pragma unroll
        for (int kt = 0; kt < 4; ++kt) st[kt] = (floatx4){0.f, 0.f, 0.f, 0.f};
        __builtin_amdgcn_s_setprio(1);
#pragma unroll
        for (int kt = 0; kt < 4; ++kt) {
            st[kt] = mfma16(ka0[kt], qfr0, st[kt]);
            st[kt] = mfma16(ka1[kt], qfr1, st[kt]);
        }
        __builtin_amdgcn_s_setprio(0);
        const float SC = 0.18033688011112042f;   // 0.125 * log2(e)
        float sv[4][4];
        float bmax = -1e30f;
        if (rem >= 80) {                // interior: causal always satisfied
#pragma unroll
            for (int kt = 0; kt < 4; ++kt)
#pragma unroll
                for (int r = 0; r < 4; ++r) {
                    float s = st[kt][r] * SC;
                    sv[kt][r] = s;
                    bmax = fmaxf(bmax, s);
                }
        } else {
#pragma unroll
            for (int kt = 0; kt < 4; ++kt)
#pragma unroll
                for (int r = 0; r < 4; ++r) {
                    int k = n0 + kt * 16 + lq * 4 + r;
                    float s = (k <= qt0 + lr) ? st[kt][r] * SC : -1e30f;
                    sv[kt][r] = s;
                    bmax = fmaxf(bmax, s);
                }
        }
        bmax = fmaxf(bmax, __shfl_xor(bmax, 16));
        bmax = fmaxf(bmax, __shfl_xor(bmax, 32));
        float mn = fmaxf(m, bmax);
        float alpha = __builtin_amdgcn_exp2f(m - mn);
        m = mn;
        float ps = 0.f;
#pragma unroll
        for (int kt = 0; kt < 4; ++kt) {
            float p0 = __builtin_amdgcn_exp2f(sv[kt][0] - mn);
            float p1 = __builtin_amdgcn_exp2f(sv[kt][1] - mn);
            float p2 = __builtin_amdgcn_exp2f(sv[kt][2] - mn);
            float p3 = __builtin_amdgcn_exp2f(sv[kt][3] - mn);
            ps += (p0 + p1) + (p2 + p3);
            unsigned wlo, whi;
            asm("v_cvt_pk_bf16_f32 %0, %1, %2" : "=v"(wlo) : "v"(p0), "v"(p1));
            asm("v_cvt_pk_bf16_f32 %0, %1, %2" : "=v"(whi) : "v"(p2), "v"(p3));
            *(uint2*)&lp[lr * PSTR + kt * 16 + lq * 4] = (uint2){wlo, whi};
        }
        ps += __shfl_xor(ps, 16);
        ps += __shfl_xor(ps, 32);
        l = l * alpha + ps;
        float af[4];
#pragma unroll
        for (int r = 0; r < 4; ++r) af[r] = __shfl(alpha, lq * 4 + r);
#pragma unroll
        for (int r = 0; r < 4; ++r) {
            o0[r] *= af[r]; o1[r] *= af[r]; o2[r] *= af[r]; o3[r] *= af[r];
        }
        asm volatile("s_waitcnt lgkmcnt(0)" ::: "memory");
        // PV: masked P entries are exactly 0 -> unconditional both halves
        __builtin_amdgcn_s_setprio(1);
#pragma unroll
        for (int c = 0; c < 2; ++c) {
            uint2 plo = *(const uint2*)&lp[lr * PSTR + c * 32 + lk];
            uint2 phi = *(const uint2*)&lp[lr * PSTR + c * 32 + lk + 4];
            short8 pfr = __builtin_bit_cast(short8, (uint4){plo.x, plo.y, phi.x, phi.y});
            o0 = mfma16(pfr, vv[c][0], o0);
            o1 = mfma16(pfr, vv[c][1], o1);
            o2 = mfma16(pfr, vv[c][2], o2);
            o3 = mfma16(pfr, vv[c][3], o3);
        }
        __builtin_amdgcn_s_setprio(0);
#pragma unroll
        for (int kt = 0; kt < 4; ++kt) { ka0[kt] = kn0[kt]; ka1[kt] = kn1[kt]; }
    }
    float li[4];
#pragma unroll
    for (int r = 0; r < 4; ++r) li[r] = 1.0f / __shfl(l, lq * 4 + r);
    int b = hid >> 4, h = hid & 15;
    size_t orow_base = ((size_t)b * S_ + qt0 + lq * 4) * E_ + h * D_;
#pragma unroll
    for (int r = 0; r < 4; ++r) {
        size_t rb = orow_base + (size_t)r * E_;
        ab[rb + 0  + lr] = f2bf(o0[r] * li[r]);
        ab[rb + 16 + lr] = f2bf(o1[r] * li[r]);
        ab[rb + 32 + lr] = f2bf(o2[r] * li[r]);
        ab[rb + 48 + lr] = f2bf(o3[r] * li[r]);
    }
}

// ---------------- top-8 tiles from last-row logits (fp32 path) ----------------
__global__ __launch_bounds__(256) void topk_kernel(const float* __restrict__ qlast,
                                                   const float* __restrict__ kf,
                                                   const float* __restrict__ kfl1,
                                                   const float* __restrict__ kfl2,
                                                   const float* __restrict__ cost,
                                                   const float* __restrict__ sint,
                                                   float* __restrict__ oidx) {
    __shared__ float qr[64];
    __shared__ float lmax[256];
    __shared__ float tmax[128];
    int bx = blockIdx.x;            // b*16 + h
    int h = bx & 15, b = bx >> 4;
    int tid = threadIdx.x;
    if (tid < 32) {
        float c = cost[2047 * 32 + tid], sn = sint[2047 * 32 + tid];
        float q0 = qlast[(size_t)b * E_ + h * 64 + 2 * tid];
        float q1 = qlast[(size_t)b * E_ + h * 64 + 2 * tid + 1];
        qr[2 * tid]     = q0 * c - q1 * sn;
        qr[2 * tid + 1] = q0 * sn + q1 * c;
    }
    __syncthreads();
    float best = -1e30f;
    for (int j = 0; j < 8; ++j) {
        int s = tid * 8 + j;
        size_t kbase = ((size_t)b * S_ + s) * E_ + h * 64;
        const float* kr  = &kf[kbase];
        const float* kr1 = &kfl1[kbase];
        const float* kr2 = &kfl2[kbase];
        float acc = 0.f;
#pragma unroll
        for (int i = 0; i < 32; ++i) {
            float c = cost[s * 32 + i], sn = sint[s * 32 + i];
            float k0 = (kr[2 * i] + kr1[2 * i]) + kr2[2 * i];
            float k1 = (kr[2 * i + 1] + kr1[2 * i + 1]) + kr2[2 * i + 1];
            acc += qr[2 * i] * (k0 * c - k1 * sn) + qr[2 * i + 1] * (k0 * sn + k1 * c);
        }
        best = fmaxf(best, acc);
    }
    lmax[tid] = best;
    __syncthreads();
    if (tid < 128) tmax[tid] = fmaxf(lmax[2 * tid], lmax[2 * tid + 1]);
    __syncthreads();
    if (tid < 64) {                  // wave-parallel top-8 with lowest-index tiebreak
        float v0 = tmax[tid], v1 = tmax[tid + 64];
        float va, vb; int ia, ib;
        if (v1 > v0) { va = v1; ia = tid + 64; vb = v0; ib = tid; }
        else         { va = v0; ia = tid;      vb = v1; ib = tid + 64; }
        float cv = va; int ci = ia; int used = 0;
        for (int t = 0; t < 8; ++t) {
            float bv = cv; int bi = ci;
#pragma unroll
            for (int mk = 1; mk < 64; mk <<= 1) {
                float ov = __shfl_xor(bv, mk);
                int oi = __shfl_xor(bi, mk);
                if (ov > bv || (ov == bv && oi < bi)) { bv = ov; bi = oi; }
            }
            if (tid == 0) oidx[bx * 8 + t] = (float)bi;
            if (ci == bi) {
                if (used == 0) { cv = vb; ci = ib; used = 1; }
                else           { cv = -3e30f; ci = 1 << 20; }
            }
        }
    }
}

// ---------------- launch ----------------
extern "C" void kernel_launch(void* const* d_in, const int* in_sizes, int n_in,
                              void* d_out, int out_size, void* d_ws, size_t ws_size,
                              hipStream_t stream) {
    (void)in_sizes; (void)n_in; (void)out_size; (void)ws_size;
    const float* x  = (const float*)d_in[0];
    const float* wq = (const float*)d_in[1];
    const float* wk = (const float*)d_in[2];
    const float* wv = (const float*)d_in[3];
    const float* wo = (const float*)d_in[4];
    float* out = (float*)d_out;

    char* wsp = (char*)d_ws;
    size_t off = 0;
    auto nxt = [&](size_t bytes) {
        char* p = wsp + off;
        off = (off + bytes + 255) & ~(size_t)255;
        return p;
    };
    u16* xb    = (u16*)nxt((size_t)BS_ * E_ * 2);
    u16* xlb   = (u16*)nxt((size_t)BS_ * E_ * 2);
    u16* wqt   = (u16*)nxt((size_t)E_ * E_ * 2);
    u16* wkt   = (u16*)nxt((size_t)E_ * E_ * 2);
    u16* wklt  = (u16*)nxt((size_t)E_ * E_ * 2);
    u16* wvt   = (u16*)nxt((size_t)E_ * E_ * 2);
    u16* wot   = (u16*)nxt((size_t)E_ * E_ * 2);
    float* qf  = (float*)nxt((size_t)BS_ * E_ * 4);
    float* kf  = (float*)nxt((size_t)BS_ * E_ * 4);
    float* kfl1 = (float*)nxt((size_t)BS_ * E_ * 4);
    float* kfl2 = (float*)nxt((size_t)BS_ * E_ * 4);
    float* vf  = (float*)nxt((size_t)BS_ * E_ * 4);
    float* cost = (float*)nxt((size_t)S_ * 32 * 4);
    float* sint = (float*)nxt((size_t)S_ * 32 * 4);
    u16* qb    = (u16*)nxt((size_t)B_ * H_ * S_ * D_ * 2);
    u16* kb    = (u16*)nxt((size_t)B_ * H_ * S_ * D_ * 2);
    u16* vtb   = (u16*)nxt((size_t)B_ * H_ * S_ * D_ * 2);
    u16* ab    = (u16*)nxt((size_t)BS_ * E_ * 2);
    float* qlast = (float*)nxt((size_t)B_ * E_ * 4);

    // prep
    hipLaunchKernelGGL(rope_table_kernel, dim3(S_ * 32 / 256), dim3(256), 0, stream, cost, sint);
    hipLaunchKernelGGL(convert_x_kernel, dim3(BS_ * E_ / 4 / 256), dim3(256), 0, stream, x, xb, xlb);
    hipLaunchKernelGGL(transpose_w_kernel, dim3(1024), dim3(256), 0, stream, wq, wqt, (u16*)nullptr);
    hipLaunchKernelGGL(transpose_w_kernel, dim3(1024), dim3(256), 0, stream, wk, wkt, wklt);
    hipLaunchKernelGGL(transpose_w_kernel, dim3(1024), dim3(256), 0, stream, wv, wvt, (u16*)nullptr);
    hipLaunchKernelGGL(transpose_w_kernel, dim3(1024), dim3(256), 0, stream, wo, wot, (u16*)nullptr);

    // uniform projection passes (K split across kf/kfl1/kfl2, summed at consumers)
    hipLaunchKernelGGL(proj_gemm_kernel, dim3(1280), dim3(256), 0, stream,
                       xb, xlb, wqt, wkt, wklt, wvt, qf, kf, kfl1, kfl2, vf);
    hipLaunchKernelGGL(qlast_kernel, dim3(64), dim3(256), 0, stream, x, wq, qlast);

    // rearrange
    hipLaunchKernelGGL(rope_qk_kernel, dim3(B_ * S_ * H_ * 32 / 256), dim3(256), 0, stream,
                       qf, kf, kfl1, kfl2, cost, sint, qb, kb);
    hipLaunchKernelGGL(v_transpose_kernel, dim3(B_ * H_ * (S_ / 64)), dim3(256), 0, stream, vf, vtb);

    // attention + top-k
    hipLaunchKernelGGL(flash_kernel, dim3(B_ * H_ * (S_ / 64)), dim3(256), 0, stream, qb, kb, vtb, ab);
    hipLaunchKernelGGL(topk_kernel, dim3(B_ * H_), dim3(256), 0, stream,
                       qlast, kf, kfl1, kfl2, cost, sint, out + (size_t)BS_ * E_);

    // output projection
    hipLaunchKernelGGL(gemm_bf16_kernel, dim3(256), dim3(256), 0, stream, ab, wot, out,
                       BS_, E_, E_);
}